// Round 3
// baseline (306.141 us; speedup 1.0000x reference)
//
#include <hip/hip_runtime.h>
#include <stdint.h>

typedef unsigned short u16;
typedef __attribute__((ext_vector_type(8))) __bf16 bf16x8;
typedef __attribute__((ext_vector_type(4))) float f32x4;

#define NGROUPS 32
#define TOK 2048
#define IN_F 512
#define OUT_F 512
#define NEXP 8
#define BM 128
#define BN 128
#define BK 64

__device__ __forceinline__ u16 f2bf(float f) {
    unsigned int u = __float_as_uint(f);
    unsigned int r = (u + 0x7fffu + ((u >> 16) & 1u)) >> 16;  // RNE
    return (u16)r;
}

// ---------------- weight mixing ----------------
// Each block owns a contiguous 1024-float slice of the [512x512] weight
// matrix; loads Wsh + all 8 We slices once, then loops the 32 groups.
// mw[g][o][i] bf16 at the BASE of d_ws — total use exactly 16 MiB.
// (Round-2 failure: a bias region past 16 MiB overflowed ws and corrupted
//  the harness's pristine input copy — bias is now computed in the GEMM
//  epilogue instead.)
__global__ __launch_bounds__(256) void mix_w_kernel(
    const float* __restrict__ coeff, const float* __restrict__ We,
    const float* __restrict__ Wsh, u16* __restrict__ mw)
{
    __shared__ float cs[NGROUPS * NEXP];  // 256 floats
    int tid = threadIdx.x;
    cs[tid] = coeff[tid];
    __syncthreads();

    size_t idx = ((size_t)blockIdx.x * 256 + tid) * 4;  // 4 floats per thread
    f32x4 wsh = *(const f32x4*)(Wsh + idx);
    f32x4 we[NEXP];
#pragma unroll
    for (int e = 0; e < NEXP; ++e)
        we[e] = *(const f32x4*)(We + (size_t)e * OUT_F * IN_F + idx);

    for (int g = 0; g < NGROUPS; ++g) {
        f32x4 a = wsh;
#pragma unroll
        for (int e = 0; e < NEXP; ++e) {
            float c = cs[g * NEXP + e];
            a[0] += c * we[e][0];
            a[1] += c * we[e][1];
            a[2] += c * we[e][2];
            a[3] += c * we[e][3];
        }
        unsigned int ow[2];
        ow[0] = (unsigned int)f2bf(a[0]) | ((unsigned int)f2bf(a[1]) << 16);
        ow[1] = (unsigned int)f2bf(a[2]) | ((unsigned int)f2bf(a[3]) << 16);
        *(uint2*)(mw + (size_t)g * OUT_F * IN_F + idx) = *(const uint2*)ow;
    }
}

// ---------------- grouped GEMM ----------------
// out[g*TOK+t][o] = sum_i x[t][i] * mw[g][o][i] + bias(g,o)
// x fp32 (staged fp32 in LDS, cvt at fragment build), mw bf16, out fp32.
// Mixed bias computed inline in the epilogue (no extra ws).
__global__ __launch_bounds__(256) void gemm_kernel(
    const float* __restrict__ x, const u16* __restrict__ mw,
    const float* __restrict__ coeff, const float* __restrict__ be,
    const float* __restrict__ bsh, float* __restrict__ out)
{
    __shared__ __align__(16) float As[BM * BK];  // 32 KB [row][k] fp32
    __shared__ __align__(16) u16  Bs[BN * BK];   // 16 KB [o][k] bf16

    int bid = blockIdx.x;
    int g = bid >> 6;         // 64 blocks/group: 16 mtiles x 4 ntiles
    int t = bid & 63;
    int mtile = t >> 2;
    int ntile = t & 3;

    const float* Ag = x + ((size_t)g * TOK + (size_t)mtile * BM) * IN_F;
    const u16*   Bg = mw + (size_t)g * OUT_F * IN_F + (size_t)ntile * BN * IN_F;

    int tid  = threadIdx.x;
    int lane = tid & 63;
    int wave = tid >> 6;
    int wm = wave >> 1, wn = wave & 1;
    int lm = lane & 15, lq = lane >> 4;

    // A staging (fp32): 16B = 4 floats/thread; row = tid/16, chunk = tid%16.
    int srA = tid >> 4;
    int scA = (tid & 15) * 4;
    // B staging (bf16): 16B = 8 elems/thread; row = tid/8, chunk = tid%8.
    int srB = tid >> 3;
    int scB = (tid & 7) * 8;

    f32x4 acc[4][4];
#pragma unroll
    for (int mi = 0; mi < 4; ++mi)
#pragma unroll
        for (int ni = 0; ni < 4; ++ni)
            acc[mi][ni] = f32x4{0.f, 0.f, 0.f, 0.f};

    for (int k0 = 0; k0 < IN_F; k0 += BK) {
        __syncthreads();
#pragma unroll
        for (int p = 0; p < 8; ++p) {   // A: 8 passes x 16 rows
            int r = srA + p * 16;
            __builtin_amdgcn_global_load_lds(
                (const __attribute__((address_space(1))) void*)(Ag + (size_t)r * IN_F + k0 + scA),
                (__attribute__((address_space(3))) void*)(As + r * BK + scA),
                16, 0, 0);
        }
#pragma unroll
        for (int p = 0; p < 4; ++p) {   // B: 4 passes x 32 rows
            int r = srB + p * 32;
            __builtin_amdgcn_global_load_lds(
                (const __attribute__((address_space(1))) void*)(Bg + (size_t)r * IN_F + k0 + scB),
                (__attribute__((address_space(3))) void*)(Bs + r * BK + scB),
                16, 0, 0);
        }
        __syncthreads();

#pragma unroll
        for (int ks = 0; ks < 2; ++ks) {
            bf16x8 af[4], bfv[4];
#pragma unroll
            for (int mi = 0; mi < 4; ++mi) {
                int base = (wm * 64 + mi * 16 + lm) * BK + ks * 32 + lq * 8;
                f32x4 a0 = *(const f32x4*)&As[base];
                f32x4 a1 = *(const f32x4*)&As[base + 4];
#pragma unroll
                for (int j = 0; j < 4; ++j) {
                    af[mi][j]     = (__bf16)a0[j];
                    af[mi][j + 4] = (__bf16)a1[j];
                }
            }
#pragma unroll
            for (int ni = 0; ni < 4; ++ni)
                bfv[ni] = *(const bf16x8*)&Bs[(wn * 64 + ni * 16 + lm) * BK + ks * 32 + lq * 8];
#pragma unroll
            for (int mi = 0; mi < 4; ++mi)
#pragma unroll
                for (int ni = 0; ni < 4; ++ni)
                    acc[mi][ni] = __builtin_amdgcn_mfma_f32_16x16x32_bf16(
                        af[mi], bfv[ni], acc[mi][ni], 0, 0, 0);
        }
    }

    // epilogue: C/D layout col=lane&15, row=(lane>>4)*4+reg  [m89/m91]
    int c0 = ntile * BN + wn * 64;
    float cg[NEXP];
#pragma unroll
    for (int e = 0; e < NEXP; ++e) cg[e] = coeff[g * NEXP + e];
    float bias[4];
#pragma unroll
    for (int ni = 0; ni < 4; ++ni) {
        int o = c0 + ni * 16 + lm;
        float v = bsh[o];
#pragma unroll
        for (int e = 0; e < NEXP; ++e) v += cg[e] * be[e * OUT_F + o];
        bias[ni] = v;
    }

    size_t rowbase = (size_t)g * TOK + (size_t)mtile * BM + (size_t)wm * 64;
#pragma unroll
    for (int mi = 0; mi < 4; ++mi) {
#pragma unroll
        for (int rr = 0; rr < 4; ++rr) {
            size_t row = rowbase + mi * 16 + lq * 4 + rr;
            float* orow = out + row * OUT_F;
#pragma unroll
            for (int ni = 0; ni < 4; ++ni)
                orow[c0 + ni * 16 + lm] = acc[mi][ni][rr] + bias[ni];
        }
    }
}

extern "C" void kernel_launch(void* const* d_in, const int* in_sizes, int n_in,
                              void* d_out, int out_size, void* d_ws, size_t ws_size,
                              hipStream_t stream) {
    const float* x     = (const float*)d_in[0];  // [65536][512] fp32
    const float* coeff = (const float*)d_in[1];  // [32][8] fp32
    const float* We    = (const float*)d_in[2];  // [8][512][512] fp32
    const float* be    = (const float*)d_in[3];  // [8][512] fp32
    const float* Wsh   = (const float*)d_in[4];  // [512][512] fp32
    const float* bsh   = (const float*)d_in[5];  // [512] fp32
    // d_in[6] = sizes (int32) — static equal groups, unused
    float* out = (float*)d_out;

    // ws: mixed weights bf16 [32][512][512] = exactly 16 MiB, nothing else.
    u16* mw = (u16*)d_ws;

    mix_w_kernel<<<OUT_F * IN_F / (256 * 4), 256, 0, stream>>>(coeff, We, Wsh, mw);

    int grid = NGROUPS * (TOK / BM) * (OUT_F / BN);  // 2048
    gemm_kernel<<<grid, 256, 0, stream>>>(x, mw, coeff, be, bsh, out);
}

// Round 4
// 293.377 us; speedup vs baseline: 1.0435x; 1.0435x over previous
//
#include <hip/hip_runtime.h>
#include <stdint.h>

typedef unsigned short u16;
typedef __attribute__((ext_vector_type(8))) __bf16 bf16x8;
typedef __attribute__((ext_vector_type(4))) __bf16 bf16x4;
typedef __attribute__((ext_vector_type(4))) float f32x4;

#define NGROUPS 32
#define TOK 2048
#define IN_F 512
#define OUT_F 512
#define NEXP 8
#define BM 128
#define BN 128
#define BK 64

__device__ __forceinline__ u16 f2bf(float f) {
    unsigned int u = __float_as_uint(f);
    unsigned int r = (u + 0x7fffu + ((u >> 16) & 1u)) >> 16;  // RNE
    return (u16)r;
}

// ---------------- weight mixing ----------------
// mw[g][o][i] bf16 at base of d_ws (exactly 16 MiB — DO NOT exceed: round-2
// overflow past 16 MiB corrupted the harness's pristine inputs).
// 4-way split over group clusters for parallelism (1024 blocks).
__global__ __launch_bounds__(256) void mix_w_kernel(
    const float* __restrict__ coeff, const float* __restrict__ We,
    const float* __restrict__ Wsh, u16* __restrict__ mw)
{
    __shared__ float cs[NGROUPS * NEXP];
    int tid = threadIdx.x;
    cs[tid] = coeff[tid];
    __syncthreads();

    size_t idx = ((size_t)blockIdx.x * 256 + tid) * 4;  // 4 floats/thread
    f32x4 wsh = *(const f32x4*)(Wsh + idx);
    f32x4 we[NEXP];
#pragma unroll
    for (int e = 0; e < NEXP; ++e)
        we[e] = *(const f32x4*)(We + (size_t)e * OUT_F * IN_F + idx);

    int g0 = blockIdx.y * 8;
    for (int g = g0; g < g0 + 8; ++g) {
        f32x4 a = wsh;
#pragma unroll
        for (int e = 0; e < NEXP; ++e) {
            float c = cs[g * NEXP + e];
            a[0] += c * we[e][0];
            a[1] += c * we[e][1];
            a[2] += c * we[e][2];
            a[3] += c * we[e][3];
        }
        unsigned int ow[2];
        ow[0] = (unsigned int)f2bf(a[0]) | ((unsigned int)f2bf(a[1]) << 16);
        ow[1] = (unsigned int)f2bf(a[2]) | ((unsigned int)f2bf(a[3]) << 16);
        *(uint2*)(mw + (size_t)g * OUT_F * IN_F + idx) = *(const uint2*)ow;
    }
}

// ---------------- grouped GEMM ----------------
// out[g*TOK+t][o] = sum_i x[t][i]*mw[g][o][i] + bias(g,o)
// Both LDS tiles bf16 [row][64], XOR-swizzled: 16B chunk p = c ^ (row&7).
// A: fp32 global -> regs -> cvt -> ds_write_b64 (reg prefetch overlaps MFMA).
// B: global_load_lds, source-chunk XOR-permuted (dest stays lane-linear).
__global__ __launch_bounds__(256) void gemm_kernel(
    const float* __restrict__ x, const u16* __restrict__ mw,
    const float* __restrict__ coeff, const float* __restrict__ be,
    const float* __restrict__ bsh, float* __restrict__ out)
{
    __shared__ __align__(16) u16 As[BM * BK];  // 16 KB swizzled
    __shared__ __align__(16) u16 Bs[BN * BK];  // 16 KB swizzled

    int bid = blockIdx.x;
    // XCD swizzle: bid%8 = XCD (round-robin heuristic). Each XCD owns 4 whole
    // groups; the 4 ntile-siblings of an A-panel are consecutive on one XCD.
    int xcd = bid & 7;
    int i   = bid >> 3;                 // 0..255 within XCD
    int g = xcd * 4 + (i >> 6);
    int t = i & 63;
    int mtile = t >> 2;
    int ntile = t & 3;

    const float* Ag = x + ((size_t)g * TOK + (size_t)mtile * BM) * IN_F;
    const u16*   Bg = mw + (size_t)g * OUT_F * IN_F + (size_t)ntile * BN * IN_F;

    int tid  = threadIdx.x;
    int lane = tid & 63;
    int wave = tid >> 6;
    int wm = wave >> 1, wn = wave & 1;
    int lm = lane & 15, lq = lane >> 4;

    f32x4 acc[4][4];
#pragma unroll
    for (int mi = 0; mi < 4; ++mi)
#pragma unroll
        for (int ni = 0; ni < 4; ++ni)
            acc[mi][ni] = f32x4{0.f, 0.f, 0.f, 0.f};

    // A prefetch registers: 8 passes, thread j covers 16B fp32 chunk at
    // tile-linear chunk4 L = j*256+tid -> row=L>>4, col4=(L&15)*4. Coalesced.
    f32x4 areg[8];
#pragma unroll
    for (int j = 0; j < 8; ++j) {
        int L = j * 256 + tid;
        areg[j] = *(const f32x4*)(Ag + (size_t)(L >> 4) * IN_F + (L & 15) * 4);
    }

    for (int kk = 0; kk < IN_F / BK; ++kk) {
        int k0 = kk * BK;
        __syncthreads();  // drains A prefetch (needed now) + protects LDS

        // A: cvt + swizzled ds_write_b64 (8B = half of a 16B bf16 chunk)
#pragma unroll
        for (int j = 0; j < 8; ++j) {
            int L = j * 256 + tid;
            int r = L >> 4, c4 = L & 15;
            int p = (c4 >> 1) ^ (r & 7);
            bf16x4 bv;
            bv[0] = (__bf16)areg[j][0];
            bv[1] = (__bf16)areg[j][1];
            bv[2] = (__bf16)areg[j][2];
            bv[3] = (__bf16)areg[j][3];
            *(bf16x4*)(As + r * 64 + p * 8 + (c4 & 1) * 4) = bv;
        }
        // B: async global->LDS; dest linear in tid (HW constraint), source
        // chunk XOR-permuted within the 128B row segment (stays coalesced).
#pragma unroll
        for (int q = 0; q < 4; ++q) {
            int r = q * 32 + (tid >> 3);
            int c = (tid & 7) ^ (r & 7);
            __builtin_amdgcn_global_load_lds(
                (const __attribute__((address_space(1))) void*)(Bg + (size_t)r * IN_F + k0 + c * 8),
                (__attribute__((address_space(3))) void*)(Bs + ((size_t)q * 256 + tid) * 8),
                16, 0, 0);
        }
        __syncthreads();  // drains B staging (16 KB) + A ds_writes

        // issue next A prefetch AFTER the drain barrier: stays in flight
        // across the whole MFMA section, drained at next iter's barrier-1.
        if (kk + 1 < IN_F / BK) {
#pragma unroll
            for (int j = 0; j < 8; ++j) {
                int L = j * 256 + tid;
                areg[j] = *(const f32x4*)(Ag + (size_t)(L >> 4) * IN_F + (k0 + BK) + (L & 15) * 4);
            }
        }

#pragma unroll
        for (int ks = 0; ks < 2; ++ks) {
            bf16x8 af[4], bfv[4];
#pragma unroll
            for (int mi = 0; mi < 4; ++mi) {
                int r = wm * 64 + mi * 16 + lm;
                int p = (ks * 4 + lq) ^ (r & 7);
                af[mi] = *(const bf16x8*)(As + r * 64 + p * 8);
            }
#pragma unroll
            for (int ni = 0; ni < 4; ++ni) {
                int r = wn * 64 + ni * 16 + lm;
                int p = (ks * 4 + lq) ^ (r & 7);
                bfv[ni] = *(const bf16x8*)(Bs + r * 64 + p * 8);
            }
#pragma unroll
            for (int mi = 0; mi < 4; ++mi)
#pragma unroll
                for (int ni = 0; ni < 4; ++ni)
                    acc[mi][ni] = __builtin_amdgcn_mfma_f32_16x16x32_bf16(
                        af[mi], bfv[ni], acc[mi][ni], 0, 0, 0);
        }
    }

    // epilogue: C/D layout col=lane&15, row=(lane>>4)*4+reg  [m89/m91]
    int c0 = ntile * BN + wn * 64;
    float cg[NEXP];
#pragma unroll
    for (int e = 0; e < NEXP; ++e) cg[e] = coeff[g * NEXP + e];
    float bias[4];
#pragma unroll
    for (int ni = 0; ni < 4; ++ni) {
        int o = c0 + ni * 16 + lm;
        float v = bsh[o];
#pragma unroll
        for (int e = 0; e < NEXP; ++e) v += cg[e] * be[e * OUT_F + o];
        bias[ni] = v;
    }

    size_t rowbase = (size_t)g * TOK + (size_t)mtile * BM + (size_t)wm * 64;
#pragma unroll
    for (int mi = 0; mi < 4; ++mi) {
#pragma unroll
        for (int rr = 0; rr < 4; ++rr) {
            size_t row = rowbase + mi * 16 + lq * 4 + rr;
            float* orow = out + row * OUT_F;
#pragma unroll
            for (int ni = 0; ni < 4; ++ni)
                orow[c0 + ni * 16 + lm] = acc[mi][ni][rr] + bias[ni];
        }
    }
}

extern "C" void kernel_launch(void* const* d_in, const int* in_sizes, int n_in,
                              void* d_out, int out_size, void* d_ws, size_t ws_size,
                              hipStream_t stream) {
    const float* x     = (const float*)d_in[0];  // [65536][512] fp32
    const float* coeff = (const float*)d_in[1];  // [32][8]
    const float* We    = (const float*)d_in[2];  // [8][512][512]
    const float* be    = (const float*)d_in[3];  // [8][512]
    const float* Wsh   = (const float*)d_in[4];  // [512][512]
    const float* bsh   = (const float*)d_in[5];  // [512]
    float* out = (float*)d_out;

    u16* mw = (u16*)d_ws;  // bf16 [32][512][512] = exactly 16 MiB

    mix_w_kernel<<<dim3(OUT_F * IN_F / (256 * 4), 4), 256, 0, stream>>>(coeff, We, Wsh, mw);

    int grid = NGROUPS * (TOK / BM) * (OUT_F / BN);  // 2048
    gemm_kernel<<<grid, 256, 0, stream>>>(x, mw, coeff, be, bsh, out);
}